// Round 1
// 1209.535 us; speedup vs baseline: 1.0115x; 1.0115x over previous
//
#include <hip/hip_runtime.h>
#include <hip/hip_bf16.h>
#include <cstdint>

#define FEAT 2048
#define NH 32
#define DIN 2112          // FEAT + 2*H
#define NE 8
#define ED 32
#define HID 1024
#define VOCAB 50257
#define NPAD 50304        // 393 * 128

typedef __attribute__((ext_vector_type(8))) short short8;
typedef __attribute__((ext_vector_type(4))) float f32x4;

// ---------------------------------------------------------------------------
// Kernel A: per-row pipeline. One block per batch row.
// mean -> phasor -> enhanced (LDS) -> gate softmax -> expert dots -> mix ->
// ctx = tanh(mixed @ Wo + bo)  (all fp32)
// ---------------------------------------------------------------------------
__global__ __launch_bounds__(256) void rowpipe_kernel(
    const float* __restrict__ x, const float* __restrict__ Wg,
    const float* __restrict__ bg, const float* __restrict__ We,
    const float* __restrict__ be, const float* __restrict__ Wo,
    const float* __restrict__ bo, float* __restrict__ ctx)
{
  __shared__ __align__(16) float sEnh[DIN];
  __shared__ float sRed[256];
  __shared__ float sGate[NE];
  __shared__ float sMix[NE][ED];
  __shared__ float sMixed[ED];
  __shared__ float sS;

  const int t = threadIdx.x;
  const int b = blockIdx.x;

  // --- 1. load x row into LDS + row sum ---
  const float4* x4 = (const float4*)(x + (size_t)b * FEAT);
  float4* e4 = (float4*)sEnh;
  float ls = 0.f;
#pragma unroll
  for (int q = 0; q < 2; ++q) {
    int i = t + q * 256;          // 0..511 float4s
    float4 v = x4[i];
    e4[i] = v;
    ls += v.x + v.y + v.z + v.w;
  }
  sRed[t] = ls;
  __syncthreads();
  for (int off = 128; off > 0; off >>= 1) {
    if (t < off) sRed[t] += sRed[t + off];
    __syncthreads();
  }
  if (t == 0) sS = sRed[0] * (1.f / FEAT);
  __syncthreads();

  // --- 2. phasor features ---
  if (t < 64) {
    float s = sS;
    int k = (t & 31) + 1;
    float ph = (43.98229715025711f * s) * (float)k;   // 2*pi*delta0 in f32
    sEnh[FEAT + t] = (t < 32) ? cosf(ph) : sinf(ph);
  }
  __syncthreads();

  // --- 3. gate logits + softmax ---
  {
    int e = t & 7, g = t >> 3;    // 32 groups of 8
    float p = 0.f;
    for (int d = g; d < DIN; d += 32) p += sEnh[d] * Wg[d * NE + e];
    sRed[t] = p;
    __syncthreads();
    if (t < NE) {
      float sum = bg[t];
#pragma unroll
      for (int g2 = 0; g2 < 32; ++g2) sum += sRed[g2 * 8 + t];
      sGate[t] = sum;             // logits
    }
    __syncthreads();
    if (t == 0) {
      float mx = sGate[0];
#pragma unroll
      for (int e2 = 1; e2 < NE; ++e2) mx = fmaxf(mx, sGate[e2]);
      float tmp[NE];
      float ssum = 0.f;
#pragma unroll
      for (int e2 = 0; e2 < NE; ++e2) { tmp[e2] = expf(sGate[e2] - mx); ssum += tmp[e2]; }
      float inv = 1.f / ssum;
#pragma unroll
      for (int e2 = 0; e2 < NE; ++e2) sGate[e2] = tmp[e2] * inv;
    }
    __syncthreads();
  }

  // --- 5. expert dot products; thread (e,h) ---
  {
    int e = t >> 5, h = t & 31;
    const float* Wep = We + (size_t)e * DIN * ED + h;
    float acc = be[e * ED + h];
    const float4* sE4 = (const float4*)sEnh;
#pragma unroll 4
    for (int d4 = 0; d4 < DIN / 4; ++d4) {
      float4 ev = sE4[d4];
      const float* wp = Wep + (size_t)(d4 * 4) * ED;
      acc = fmaf(ev.x, wp[0], acc);
      acc = fmaf(ev.y, wp[ED], acc);
      acc = fmaf(ev.z, wp[2 * ED], acc);
      acc = fmaf(ev.w, wp[3 * ED], acc);
    }
    sMix[e][h] = sGate[e] * acc;
  }
  __syncthreads();
  if (t < ED) {
    float m = 0.f;
#pragma unroll
    for (int e2 = 0; e2 < NE; ++e2) m += sMix[e2][t];
    sMixed[t] = m;
  }
  __syncthreads();

  // --- 6. ctx = tanh(mixed @ Wo + bo) ---
#pragma unroll
  for (int jj = 0; jj < 4; ++jj) {
    int j = t + jj * 256;
    float acc = bo[j];
#pragma unroll
    for (int kk = 0; kk < ED; ++kk) acc = fmaf(sMixed[kk], Wo[kk * HID + j], acc);
    ctx[(size_t)b * HID + j] = tanhf(acc);
  }
}

// ---------------------------------------------------------------------------
// Kernel B: top-20 selection from ctx[0] (argsort semantics) + spiking sim
// -> gains[1024]. Single block.
// ---------------------------------------------------------------------------
__global__ __launch_bounds__(256) void select_spike_kernel(
    const float* __restrict__ ctx, float* __restrict__ gains)
{
  __shared__ float v[HID];
  __shared__ float rv[256];
  __shared__ int   ri[256];
  __shared__ int   tok[20];

  const int t = threadIdx.x;
#pragma unroll
  for (int q = 0; q < 4; ++q) v[t + q * 256] = ctx[t + q * 256];
#pragma unroll
  for (int q = 0; q < 4; ++q) gains[t + q * 256] = 1.0f;
  __syncthreads();

  // 20 iterations of block-wide argmax by (value, index) lexicographic.
  // Stable ascending argsort => among equal values larger index is "later",
  // so ties are broken toward larger index when picking from the top.
  for (int sel = 0; sel < 20; ++sel) {
    float bv = -2e30f; int bi = -1;
#pragma unroll
    for (int q = 0; q < 4; ++q) {
      int idx = t + q * 256; float xv = v[idx];
      if (xv > bv || (xv == bv && idx > bi)) { bv = xv; bi = idx; }
    }
    rv[t] = bv; ri[t] = bi;
    __syncthreads();
    for (int off = 128; off > 0; off >>= 1) {
      if (t < off) {
        if (rv[t + off] > rv[t] || (rv[t + off] == rv[t] && ri[t + off] > ri[t])) {
          rv[t] = rv[t + off]; ri[t] = ri[t + off];
        }
      }
      __syncthreads();
    }
    if (t == 0) { tok[19 - sel] = ri[0]; v[ri[0]] = -3e30f; }
    __syncthreads();
  }

  // LIF k-winner simulation over the 20 unique tokens (all other vocab
  // entries stay 0 and can never spike: spk requires v >= 1).
  if (t == 0) {
    float vv[20], cn[20];
    for (int j = 0; j < 20; ++j) { vv[j] = 0.f; cn[j] = 0.f; }
    for (int st = 0; st < 20; ++st) {
      for (int j = 0; j < 20; ++j) vv[j] *= 0.7f;   // DECAY
      vv[st] += 1.0f;
      bool picked[20];
      for (int j = 0; j < 20; ++j) picked[j] = false;
      for (int w = 0; w < 5; ++w) {                 // K_WINNERS
        int best = -1; float bvv = 0.f;
        for (int j = 0; j < 20; ++j) {
          if (picked[j]) continue;
          if (vv[j] > bvv ||
              (best >= 0 && vv[j] == bvv && vv[j] > 0.f && tok[j] < tok[best])) {
            best = j; bvv = vv[j];
          }
        }
        if (best < 0 || bvv <= 0.f) break;          // rest are zeros: no-ops
        picked[best] = true;
        if (bvv >= 1.0f) { cn[best] += 1.f; vv[best] = 0.f; }  // THETA
      }
    }
    for (int j = 0; j < 20; ++j) gains[tok[j]] += cn[j];
  }
}

// ---------------------------------------------------------------------------
// Kernel C: A_bf16[b][h] = bf16(ctx[b][h] * gains[h])
// ---------------------------------------------------------------------------
__global__ __launch_bounds__(256) void make_a_kernel(
    const float* __restrict__ ctx, const float* __restrict__ gains,
    __hip_bfloat16* __restrict__ A)
{
  const int b = blockIdx.x;
  const int h0 = threadIdx.x * 4;
  float4 cv = *(const float4*)&ctx[(size_t)b * HID + h0];
  float4 gv = *(const float4*)&gains[h0];
  union { __hip_bfloat16 h[4]; uint2 u; } p;
  p.h[0] = __float2bfloat16(cv.x * gv.x);
  p.h[1] = __float2bfloat16(cv.y * gv.y);
  p.h[2] = __float2bfloat16(cv.z * gv.z);
  p.h[3] = __float2bfloat16(cv.w * gv.w);
  *(uint2*)&A[(size_t)b * HID + h0] = p.u;
}

// ---------------------------------------------------------------------------
// Kernel D: transpose-convert Wout[1024][50257] f32 -> WT[50304][1024] bf16
// (rows >= VOCAB zero-filled)
// ---------------------------------------------------------------------------
__global__ __launch_bounds__(256) void wt_kernel(
    const float* __restrict__ Wout, __hip_bfloat16* __restrict__ WT)
{
  __shared__ float tile[32][33];
  const int n0 = blockIdx.x * 32;
  const int k0 = blockIdx.y * 32;
  const int tx = threadIdx.x & 31, ty = threadIdx.x >> 5;   // ty 0..7
#pragma unroll
  for (int i = 0; i < 4; ++i) {
    int k = k0 + ty + i * 8;
    int n = n0 + tx;
    tile[ty + i * 8][tx] = (n < VOCAB) ? Wout[(size_t)k * VOCAB + n] : 0.f;
  }
  __syncthreads();
#pragma unroll
  for (int i = 0; i < 4; ++i) {
    int n = n0 + ty + i * 8;
    int k = k0 + tx;
    WT[(size_t)n * HID + k] = __float2bfloat16(tile[tx][ty + i * 8]);
  }
}

// ---------------------------------------------------------------------------
// Kernel E: C[2048][50257] = A[2048][1024] @ WT[50304][1024]^T + bout
// m97-style: 128x128 tile, BK=32, 16x16x32 bf16 MFMA, global_load_lds w=16.
// R1: 1-D grid + bijective XCD swizzle (6288 % 8 == 0), M-tile fastest
// within each XCD chunk -> the 16 M-blocks sharing a B-panel are co-resident
// on one XCD; B (103 MB) fetched ~once instead of ~8x.
// ---------------------------------------------------------------------------
#define GL2LDS(g, l) __builtin_amdgcn_global_load_lds( \
    (const __attribute__((address_space(1))) void*)(g), \
    (__attribute__((address_space(3))) void*)(l), 16, 0, 0)

#define NTILES_M 16               // 2048 / 128
#define NTILES_N (NPAD / 128)     // 393
#define NWG (NTILES_M * NTILES_N) // 6288, divisible by 8

__global__ __launch_bounds__(256) void gemm_kernel(
    const __hip_bfloat16* __restrict__ A, const __hip_bfloat16* __restrict__ BT,
    const float* __restrict__ bout, float* __restrict__ C)
{
  __shared__ __align__(16) __hip_bfloat16 sA[128 * 32];
  __shared__ __align__(16) __hip_bfloat16 sB[128 * 32];

  const int t = threadIdx.x;
  const int lane = t & 63, wave = t >> 6;

  // XCD-aware swizzle: each XCD gets a contiguous chunk of tiles,
  // M fastest inside the chunk (B-panel reuse across the 16 M-blocks).
  const int gid = blockIdx.x;
  const int chunk = NWG / 8;                       // 786
  const int swz = (gid & 7) * chunk + (gid >> 3);  // bijective: NWG % 8 == 0
  const int m0 = (swz & (NTILES_M - 1)) * 128;
  const int n0 = (swz / NTILES_M) * 128;

  const int wm = (wave & 1) * 64, wn = (wave >> 1) * 64;
  const int lr = lane & 15, quad = lane >> 4;

  f32x4 acc[4][4];
#pragma unroll
  for (int i = 0; i < 4; ++i)
#pragma unroll
    for (int j = 0; j < 4; ++j) acc[i][j] = (f32x4){0.f, 0.f, 0.f, 0.f};

  // staging: per wave-issue 1024B = 16 rows x 64B; lane -> row lane>>2, chunk lane&3
  const int srow = wave * 16 + (lane >> 2);
  const int scol = (lane & 3) * 8;                 // bf16 elements
  const __hip_bfloat16* agp0 = A  + (size_t)(m0 + srow) * HID + scol;
  const __hip_bfloat16* agp1 = agp0 + (size_t)64 * HID;
  const __hip_bfloat16* bgp0 = BT + (size_t)(n0 + srow) * HID + scol;
  const __hip_bfloat16* bgp1 = bgp0 + (size_t)64 * HID;
  __hip_bfloat16* al0 = sA + wave * 512;           // elements (x2 bytes = 1024B)
  __hip_bfloat16* al1 = sA + 2048 + wave * 512;
  __hip_bfloat16* bl0 = sB + wave * 512;
  __hip_bfloat16* bl1 = sB + 2048 + wave * 512;

  for (int k0 = 0; k0 < HID; k0 += 32) {
    __syncthreads();                               // LDS safe to overwrite
    GL2LDS(agp0 + k0, al0);
    GL2LDS(agp1 + k0, al1);
    GL2LDS(bgp0 + k0, bl0);
    GL2LDS(bgp1 + k0, bl1);
    __syncthreads();                               // drains vmcnt before barrier

    short8 af[4], bf[4];
#pragma unroll
    for (int i = 0; i < 4; ++i)
      af[i] = *(const short8*)&sA[(wm + i * 16 + lr) * 32 + quad * 8];
#pragma unroll
    for (int j = 0; j < 4; ++j)
      bf[j] = *(const short8*)&sB[(wn + j * 16 + lr) * 32 + quad * 8];
#pragma unroll
    for (int i = 0; i < 4; ++i)
#pragma unroll
      for (int j = 0; j < 4; ++j)
        acc[i][j] = __builtin_amdgcn_mfma_f32_16x16x32_bf16(af[i], bf[j], acc[i][j], 0, 0, 0);
  }

  // epilogue: C/D layout col = lane&15 (n), row = quad*4 + reg (m)
#pragma unroll
  for (int j = 0; j < 4; ++j) {
    int n = n0 + wn + j * 16 + lr;
    if (n >= VOCAB) continue;
    float bb = bout[n];
#pragma unroll
    for (int i = 0; i < 4; ++i) {
      int m = m0 + wm + i * 16 + quad * 4;
#pragma unroll
      for (int rr = 0; rr < 4; ++rr)
        C[(size_t)(m + rr) * VOCAB + n] = acc[i][j][rr] + bb;
    }
  }
}

// ---------------------------------------------------------------------------
extern "C" void kernel_launch(void* const* d_in, const int* in_sizes, int n_in,
                              void* d_out, int out_size, void* d_ws, size_t ws_size,
                              hipStream_t stream)
{
  const float* x    = (const float*)d_in[0];
  const float* Wg   = (const float*)d_in[1];
  const float* bg   = (const float*)d_in[2];
  const float* We   = (const float*)d_in[3];
  const float* be   = (const float*)d_in[4];
  const float* Wo   = (const float*)d_in[5];
  const float* bo   = (const float*)d_in[6];
  const float* Wout = (const float*)d_in[7];
  const float* bout = (const float*)d_in[8];
  float* out = (float*)d_out;

  char* ws = (char*)d_ws;
  float*          ctx   = (float*)ws;                          // 8 MB
  float*          gains = (float*)(ws + 8388608);              // 4 KB
  __hip_bfloat16* Abf   = (__hip_bfloat16*)(ws + 8392704);     // 4 MB
  __hip_bfloat16* WT    = (__hip_bfloat16*)(ws + 12587008);    // 103 MB

  rowpipe_kernel<<<2048, 256, 0, stream>>>(x, Wg, bg, We, be, Wo, bo, ctx);
  select_spike_kernel<<<1, 256, 0, stream>>>(ctx, gains);
  make_a_kernel<<<2048, 256, 0, stream>>>(ctx, gains, Abf);
  wt_kernel<<<dim3(1572, 32), 256, 0, stream>>>(Wout, WT);
  gemm_kernel<<<dim3(NWG, 1), 256, 0, stream>>>(Abf, WT, bout, out);
}